// Round 1
// baseline (370.707 us; speedup 1.0000x reference)
//
#include <hip/hip_runtime.h>
#include <hip/hip_bf16.h>

#define C_OUT 96
#define FEAT_DIM 48
#define HW 256
#define RES 65536           // C_OUT*HW*HW / 96 rows in fa
#define IMG_C 3

// ---------------------------------------------------------------------------
// Stage 1: 3x3 SAME conv (cross-correlation), NCHW in / NCHW out + bias.
// feat[c*65536 + h*256 + w]. The reshape(-1,96) in the reference is a flat
// reinterpretation, so this buffer IS the gather table fa (row r = 96 floats
// starting at r*96).
// ---------------------------------------------------------------------------
__global__ __launch_bounds__(256) void conv_kernel(
    const float* __restrict__ img,     // [3,256,256]
    const float* __restrict__ w,       // [96,3,3,3]
    const float* __restrict__ b,       // [96]
    float* __restrict__ feat)          // [96,256,256]
{
    __shared__ float ws[C_OUT * 27];
    __shared__ float bs[C_OUT];
    for (int i = threadIdx.x; i < C_OUT * 27; i += blockDim.x) ws[i] = w[i];
    for (int i = threadIdx.x; i < C_OUT; i += blockDim.x) bs[i] = b[i];
    __syncthreads();

    int idx = blockIdx.x * blockDim.x + threadIdx.x;
    if (idx >= C_OUT * HW * HW) return;
    int c  = idx >> 16;          // / 65536
    int h  = (idx >> 8) & 255;
    int wc = idx & 255;

    float acc = bs[c];
    const float* wk = &ws[c * 27];
#pragma unroll
    for (int ci = 0; ci < IMG_C; ++ci) {
#pragma unroll
        for (int kh = 0; kh < 3; ++kh) {
            int hh = h + kh - 1;
            if (hh < 0 || hh > 255) continue;
            const float* irow = img + ci * (HW * HW) + hh * HW;
#pragma unroll
            for (int kw = 0; kw < 3; ++kw) {
                int ww = wc + kw - 1;
                if (ww < 0 || ww > 255) continue;
                acc = fmaf(irow[ww], wk[ci * 9 + kh * 3 + kw], acc);
            }
        }
    }
    feat[idx] = acc;
}

// ---------------------------------------------------------------------------
// Stage 2: per-point dual 1-D interpolation gather.
// 12 threads per point; each thread handles one float4 (4 of the 48 outputs).
// fx[r][j] = fa[r*96 + j], fy[r][j] = fa[r*96 + 48 + j].
// ---------------------------------------------------------------------------
__global__ __launch_bounds__(256) void interp_kernel(
    const float* __restrict__ pts,   // [N,2]
    const float* __restrict__ fa,    // [65536, 96] flat
    float* __restrict__ out,         // [N, 48]
    int npts)
{
    int t = blockIdx.x * blockDim.x + threadIdx.x;
    int pt = t / 12;
    int q  = t % 12;
    if (pt >= npts) return;

    float px = pts[2 * pt];
    float py = pts[2 * pt + 1];
    float x = px * 65535.0f;
    float y = py * 65535.0f;
    // reference: clip(x, 0, res-1-1e-5); in fp32 the hi bound rounds to 65535.0
    x = fminf(fmaxf(x, 0.0f), 65535.0f);
    y = fminf(fmaxf(y, 0.0f), 65535.0f);

    int x1 = (int)floorf(x);
    int y1 = (int)floorf(y);
    if (x1 > RES - 1) x1 = RES - 1;
    if (y1 > RES - 1) y1 = RES - 1;
    int x2 = min(x1 + 1, RES - 1);
    int y2 = min(y1 + 1, RES - 1);

    float xw1 = (float)x2 - x;
    float xw2 = x - (float)x1;
    float yw1 = (float)y2 - y;
    float yw2 = y - (float)y1;

    const float4* rx1 = (const float4*)(fa + (size_t)x1 * C_OUT);
    const float4* rx2 = (const float4*)(fa + (size_t)x2 * C_OUT);
    const float4* ry1 = (const float4*)(fa + (size_t)y1 * C_OUT + FEAT_DIM);
    const float4* ry2 = (const float4*)(fa + (size_t)y2 * C_OUT + FEAT_DIM);

    float4 a = rx1[q];
    float4 b = rx2[q];
    float4 c = ry1[q];
    float4 d = ry2[q];

    float4 r;
    r.x = xw1 * a.x + xw2 * b.x + yw1 * c.x + yw2 * d.x;
    r.y = xw1 * a.y + xw2 * b.y + yw1 * c.y + yw2 * d.y;
    r.z = xw1 * a.z + xw2 * b.z + yw1 * c.z + yw2 * d.z;
    r.w = xw1 * a.w + xw2 * b.w + yw1 * c.w + yw2 * d.w;

    ((float4*)(out + (size_t)pt * FEAT_DIM))[q] = r;
}

extern "C" void kernel_launch(void* const* d_in, const int* in_sizes, int n_in,
                              void* d_out, int out_size, void* d_ws, size_t ws_size,
                              hipStream_t stream) {
    const float* pts    = (const float*)d_in[0];  // [N,2]
    const float* image  = (const float*)d_in[1];  // [1,3,256,256]
    const float* conv_w = (const float*)d_in[2];  // [96,3,3,3]
    const float* conv_b = (const float*)d_in[3];  // [96]
    float* out = (float*)d_out;                   // [N,48]
    float* feat = (float*)d_ws;                   // [96,256,256] = 25.2 MB scratch

    int npts = in_sizes[0] / 2;

    {
        int total = C_OUT * HW * HW;
        int blocks = (total + 255) / 256;
        conv_kernel<<<blocks, 256, 0, stream>>>(image, conv_w, conv_b, feat);
    }
    {
        long long total = (long long)npts * 12;
        int blocks = (int)((total + 255) / 256);
        interp_kernel<<<blocks, 256, 0, stream>>>(pts, feat, out, npts);
    }
}

// Round 2
// 232.243 us; speedup vs baseline: 1.5962x; 1.5962x over previous
//
#include <hip/hip_runtime.h>
#include <hip/hip_bf16.h>

#define C_OUT 96
#define FEAT_DIM 48
#define HW 256
#define NPIX 65536          // 256*256
#define RES 65536           // rows in fa = C_OUT*NPIX/96
#define IMG_C 3

typedef __attribute__((ext_vector_type(4))) float f32x4;
typedef __attribute__((ext_vector_type(8))) unsigned short u16x8;
typedef __attribute__((ext_vector_type(4))) unsigned short u16x4;

static __device__ __forceinline__ unsigned short f2bf(float f) {
    // round-to-nearest-even f32 -> bf16
    unsigned u = __float_as_uint(f);
    u += 0x7fffu + ((u >> 16) & 1u);
    return (unsigned short)(u >> 16);
}
static __device__ __forceinline__ float bf2f(unsigned short h) {
    return __uint_as_float(((unsigned)h) << 16);
}

// ---------------------------------------------------------------------------
// Stage 1: 3x3 SAME conv (cross-correlation), NCHW. Each thread computes 4
// consecutive flat outputs (same channel, same image row since 256%4==0) and
// writes them as bf16 into the split gather tables:
//   flat index f -> row r = f/96, col j = f%96;  j<48 -> FX[r][j], else FY[r][j-48]
// A 4-aligned group of 4 never straddles the fx/fy boundary (48%4==0) nor a
// channel boundary (65536%4==0).
// ---------------------------------------------------------------------------
__global__ __launch_bounds__(256) void conv_kernel(
    const float* __restrict__ img,          // [3,256,256]
    const float* __restrict__ w,            // [96,3,3,3]
    const float* __restrict__ b,            // [96]
    unsigned short* __restrict__ FX,        // [65536,48] bf16
    unsigned short* __restrict__ FY)        // [65536,48] bf16
{
    __shared__ float ws[C_OUT * 27];
    __shared__ float bs[C_OUT];
    for (int i = threadIdx.x; i < C_OUT * 27; i += blockDim.x) ws[i] = w[i];
    for (int i = threadIdx.x; i < C_OUT; i += blockDim.x) bs[i] = b[i];
    __syncthreads();

    int tid = blockIdx.x * blockDim.x + threadIdx.x;
    if (tid >= (C_OUT * NPIX) / 4) return;
    int f = tid << 2;                // flat output index of first of 4
    int c  = f >> 16;                // channel
    int p  = f & 65535;              // pixel
    int h  = p >> 8;
    int wc = p & 255;                // multiple of 4

    float a0 = bs[c], a1 = a0, a2 = a0, a3 = a0;
#pragma unroll
    for (int ci = 0; ci < IMG_C; ++ci) {
        const float* ip = img + ci * NPIX;
#pragma unroll
        for (int kh = 0; kh < 3; ++kh) {
            int hh = h + kh - 1;
            if ((unsigned)hh >= 256u) continue;
            const float* row = ip + hh * HW;
            float win[6];
#pragma unroll
            for (int k = 0; k < 6; ++k) {
                int ww = wc + k - 1;
                win[k] = ((unsigned)ww < 256u) ? row[ww] : 0.0f;
            }
            const float* wk = &ws[c * 27 + ci * 9 + kh * 3];
#pragma unroll
            for (int kw = 0; kw < 3; ++kw) {
                float wt = wk[kw];
                a0 = fmaf(win[kw + 0], wt, a0);
                a1 = fmaf(win[kw + 1], wt, a1);
                a2 = fmaf(win[kw + 2], wt, a2);
                a3 = fmaf(win[kw + 3], wt, a3);
            }
        }
    }

    int r = (unsigned)f / 96u;
    int j = f - r * 96;
    u16x4 pk;
    pk.x = f2bf(a0); pk.y = f2bf(a1); pk.z = f2bf(a2); pk.w = f2bf(a3);
    unsigned short* dst = (j < FEAT_DIM)
        ? (FX + (size_t)r * FEAT_DIM + j)
        : (FY + (size_t)r * FEAT_DIM + (j - FEAT_DIM));
    *(u16x4*)dst = pk;
}

// ---------------------------------------------------------------------------
// Stage 2: per-point dual 1-D interpolation gather from bf16 split tables.
// 6 threads per point; each thread handles 8 features (16 B bf16x8 loads from
// each of the 4 rows, two f32x4 non-temporal stores).
// ---------------------------------------------------------------------------
__global__ __launch_bounds__(256) void interp_kernel(
    const float* __restrict__ pts,            // [N,2]
    const unsigned short* __restrict__ FX,    // [65536,48] bf16
    const unsigned short* __restrict__ FY,    // [65536,48] bf16
    float* __restrict__ out,                  // [N,48] f32
    int npts)
{
    int t = blockIdx.x * blockDim.x + threadIdx.x;
    int pt = t / 6;
    int q  = t - pt * 6;          // which 8-feature chunk
    if (pt >= npts) return;

    float px = pts[2 * pt];
    float py = pts[2 * pt + 1];
    // reference: clip(p*(res-1), 0, res-1-1e-5); hi rounds to 65535.0f in f32
    float x = fminf(fmaxf(px * 65535.0f, 0.0f), 65535.0f);
    float y = fminf(fmaxf(py * 65535.0f, 0.0f), 65535.0f);

    int x1 = (int)x;              // floor (x >= 0)
    int y1 = (int)y;
    int x2 = min(x1 + 1, RES - 1);
    int y2 = min(y1 + 1, RES - 1);

    float xw1 = (float)x2 - x;
    float xw2 = x - (float)x1;
    float yw1 = (float)y2 - y;
    float yw2 = y - (float)y1;

    const u16x8 A = *(const u16x8*)(FX + (size_t)x1 * FEAT_DIM + q * 8);
    const u16x8 B = *(const u16x8*)(FX + (size_t)x2 * FEAT_DIM + q * 8);
    const u16x8 C = *(const u16x8*)(FY + (size_t)y1 * FEAT_DIM + q * 8);
    const u16x8 D = *(const u16x8*)(FY + (size_t)y2 * FEAT_DIM + q * 8);

    float o[8];
#pragma unroll
    for (int k = 0; k < 8; ++k) {
        o[k] = xw1 * bf2f(A[k]) + xw2 * bf2f(B[k])
             + yw1 * bf2f(C[k]) + yw2 * bf2f(D[k]);
    }

    float* op = out + (size_t)pt * FEAT_DIM + q * 8;
    f32x4 v0 = {o[0], o[1], o[2], o[3]};
    f32x4 v1 = {o[4], o[5], o[6], o[7]};
    __builtin_nontemporal_store(v0, (f32x4*)op);
    __builtin_nontemporal_store(v1, (f32x4*)(op + 4));
}

extern "C" void kernel_launch(void* const* d_in, const int* in_sizes, int n_in,
                              void* d_out, int out_size, void* d_ws, size_t ws_size,
                              hipStream_t stream) {
    const float* pts    = (const float*)d_in[0];  // [N,2]
    const float* image  = (const float*)d_in[1];  // [1,3,256,256]
    const float* conv_w = (const float*)d_in[2];  // [96,3,3,3]
    const float* conv_b = (const float*)d_in[3];  // [96]
    float* out = (float*)d_out;                   // [N,48]

    unsigned short* FX = (unsigned short*)d_ws;               // 6.29 MB
    unsigned short* FY = FX + (size_t)RES * FEAT_DIM;         // 6.29 MB

    int npts = in_sizes[0] / 2;

    {
        int total = (C_OUT * NPIX) / 4;               // 1,572,864 threads
        int blocks = (total + 255) / 256;
        conv_kernel<<<blocks, 256, 0, stream>>>(image, conv_w, conv_b, FX, FY);
    }
    {
        long long total = (long long)npts * 6;
        int blocks = (int)((total + 255) / 256);
        interp_kernel<<<blocks, 256, 0, stream>>>(pts, FX, FY, out, npts);
    }
}